// Round 1
// baseline (146.086 us; speedup 1.0000x reference)
//
#include <hip/hip_runtime.h>
#include <hip/hip_bf16.h>

// Edge link-predictor: score = sigmoid(relu([h[src]|h[dst]] @ W1 + b1) @ W2 + b2)
// H=128, K=256, E=600000. bf16 MFMA (32x32x16), A gathered to LDS, W1^T in LDS.

#define HID   128
#define KTOT  256
#define NEDGE 600000
#define BE    128                      // edges per tile
#define NT    ((NEDGE + BE - 1) / BE)  // 4688 tiles
#define NBLK  512

typedef __attribute__((ext_vector_type(8)))  __bf16 bf16x8;
typedef __attribute__((ext_vector_type(16))) float  f32x16;

// round-to-nearest-even f32 -> bf16, packed pair (low word = first elem)
static __device__ __forceinline__ unsigned int pack2bf(float a, float b) {
    unsigned int ua = __float_as_uint(a);
    unsigned int ub = __float_as_uint(b);
    ua = (ua + 0x7FFFu + ((ua >> 16) & 1u)) >> 16;
    ub = (ub + 0x7FFFu + ((ub >> 16) & 1u)) >> 16;
    return (ub << 16) | (ua & 0xFFFFu);
}

__global__ __launch_bounds__(256, 1) void edge_mlp_kernel(
    const float* __restrict__ h,  const float* __restrict__ W1,
    const float* __restrict__ b1, const float* __restrict__ W2,
    const float* __restrict__ b2, const int* __restrict__ src,
    const int* __restrict__ dst,  float* __restrict__ out)
{
    // LDS: [0, 64K) = A tile [128 rows][256 k] bf16, swizzled
    //      [64K, 128K) = W1^T [128 n][256 k] bf16, swizzled
    __shared__ unsigned char smem[131072];

    const int t    = threadIdx.x;
    const int lane = t & 63;
    const int wv   = t >> 6;      // wave id == row-tile id
    const int l31  = lane & 31;
    const int l5   = lane >> 5;

    // ---- detect index width (jnp.int64 vs int32 on device) ----
    // int64 little-endian: odd dwords are high words == 0 for all values here.
    // P(false positive with genuine int32) = (1/50000)^128 ~ 0. Deterministic.
    bool idx64;
    {
        unsigned long long m =
            __ballot((src[2 * lane + 1] == 0) && (dst[2 * lane + 1] == 0));
        idx64 = (m == ~0ULL);
    }

    // ---- stage W1^T into LDS as bf16, swizzled (once per block) ----
    for (int task = t; task < 8192; task += 256) {
        int n  = task & 127;
        int kg = task >> 7;                       // 4 consecutive k per task
        const float* wp = W1 + (kg * 4) * HID + n;
        unsigned int lo = pack2bf(wp[0],       wp[HID]);
        unsigned int hi = pack2bf(wp[2 * HID], wp[3 * HID]);
        int addr = 65536 + n * 512 + ((kg * 8) ^ ((n & 7) << 4));
        *(uint2*)(smem + addr) = make_uint2(lo, hi);
    }

    // per-lane layer-2 constants: n = ct*32 + (lane&31)
    float b1v[4], w2v[4];
#pragma unroll
    for (int ct = 0; ct < 4; ++ct) {
        int n = ct * 32 + l31;
        b1v[ct] = b1[n];
        w2v[ct] = W2[n];
    }
    const float b2s = b2[0];

    for (int tile = blockIdx.x; tile < NT; tile += gridDim.x) {
        const int ebase = tile * BE;

        // ---- gather A tile: row e_local, k<128 from h[src], k>=128 from h[dst]
        // 16B chunk per thread-iter; swizzled ds_write_b128.
#pragma unroll
        for (int it = 0; it < 16; ++it) {
            int c   = it * 256 + t;
            int row = c >> 5;          // 0..127
            int o16 = c & 31;          // 16B chunk within 512B row
            int e   = ebase + row;
            if (e > NEDGE - 1) e = NEDGE - 1;   // tail clamp (stores guarded)
            int node = (o16 < 16)
                         ? (idx64 ? src[2 * e] : src[e])
                         : (idx64 ? dst[2 * e] : dst[e]);
            const float* hp = h + (long long)node * HID + (o16 & 15) * 8;
            float4 f0 = *(const float4*)hp;
            float4 f1 = *(const float4*)(hp + 4);
            uint4 w;
            w.x = pack2bf(f0.x, f0.y);
            w.y = pack2bf(f0.z, f0.w);
            w.z = pack2bf(f1.x, f1.y);
            w.w = pack2bf(f1.z, f1.w);
            int addr = row * 512 + ((o16 * 16) ^ ((row & 7) << 4));
            *(uint4*)(smem + addr) = w;
        }
        __syncthreads();

        // ---- GEMM: this wave's 32 rows x 128 cols, K=256 ----
        f32x16 acc[4];
#pragma unroll
        for (int ct = 0; ct < 4; ++ct)
#pragma unroll
            for (int r = 0; r < 16; ++r) acc[ct][r] = 0.0f;

        const int arow = wv * 32 + l31;
        const int aswz = (arow & 7) << 4;
#pragma unroll
        for (int ks = 0; ks < 16; ++ks) {
            int off = ks * 32 + l5 * 16;  // byte offset of lane's 8 bf16 k-slice
            bf16x8 af = *(const bf16x8*)(smem + arow * 512 + (off ^ aswz));
#pragma unroll
            for (int ct = 0; ct < 4; ++ct) {
                int n = ct * 32 + l31;
                bf16x8 bfg = *(const bf16x8*)(smem + 65536 + n * 512 +
                                              (off ^ ((n & 7) << 4)));
                acc[ct] = __builtin_amdgcn_mfma_f32_32x32x16_bf16(af, bfg,
                                                                  acc[ct], 0, 0, 0);
            }
        }

        // ---- epilogue: bias+relu, dot W2 partials, reduce over 32 col-lanes
        float p[16];
#pragma unroll
        for (int r = 0; r < 16; ++r) p[r] = 0.0f;
#pragma unroll
        for (int ct = 0; ct < 4; ++ct) {
#pragma unroll
            for (int r = 0; r < 16; ++r) {
                float v = acc[ct][r] + b1v[ct];
                v = v > 0.0f ? v : 0.0f;
                p[r] += v * w2v[ct];
            }
        }
#pragma unroll
        for (int r = 0; r < 16; ++r) {
            p[r] += __shfl_xor(p[r], 1);
            p[r] += __shfl_xor(p[r], 2);
            p[r] += __shfl_xor(p[r], 4);
            p[r] += __shfl_xor(p[r], 8);
            p[r] += __shfl_xor(p[r], 16);
        }
        // C/D layout: row = (reg&3) + 8*(reg>>2) + 4*(lane>>5); col = lane&31.
        // After butterfly all lanes hold the col-sum; lanes with l31==0 store.
        if (l31 == 0) {
#pragma unroll
            for (int g = 0; g < 4; ++g) {
                int e0 = ebase + wv * 32 + g * 8 + l5 * 4;
                if (e0 < NEDGE) {
                    float4 o4;
                    o4.x = 1.0f / (1.0f + __expf(-(p[4 * g + 0] + b2s)));
                    o4.y = 1.0f / (1.0f + __expf(-(p[4 * g + 1] + b2s)));
                    o4.z = 1.0f / (1.0f + __expf(-(p[4 * g + 2] + b2s)));
                    o4.w = 1.0f / (1.0f + __expf(-(p[4 * g + 3] + b2s)));
                    *(float4*)(out + e0) = o4;
                }
            }
        }
        __syncthreads();   // before next tile overwrites A
    }
}

extern "C" void kernel_launch(void* const* d_in, const int* in_sizes, int n_in,
                              void* d_out, int out_size, void* d_ws, size_t ws_size,
                              hipStream_t stream) {
    const float* h  = (const float*)d_in[0];
    const float* W1 = (const float*)d_in[1];
    const float* b1 = (const float*)d_in[2];
    const float* W2 = (const float*)d_in[3];
    const float* b2 = (const float*)d_in[4];
    const int* src  = (const int*)d_in[5];
    const int* dst  = (const int*)d_in[6];
    (void)in_sizes; (void)n_in; (void)out_size; (void)d_ws; (void)ws_size;
    edge_mlp_kernel<<<NBLK, 256, 0, stream>>>(h, W1, b1, W2, b2, src, dst,
                                              (float*)d_out);
}